// Round 9
// baseline (1236.535 us; speedup 1.0000x reference)
//
#include <hip/hip_runtime.h>
#include <hip/hip_bf16.h>

// QLSTM: T=512, B=256, D=128, H=256.  z = [x,h] @ W^T + b, W=[4H,384]
// Round 9 = round 8 (proven protocol) + three latency/BW fixes:
//  (a) W B-fragments held in VGPRs (48/lane, loaded once) -> W_s LDS deleted,
//      LDS read traffic per step halves.
//  (b) x prefetched TWO steps ahead, issued right after poll success.
//  (c) raw barriers (s_waitcnt lgkmcnt(0) + s_barrier) inside the loop instead
//      of __syncthreads -> no vmcnt(0) drain, prefetch survives the barrier.
//  Loop unrolled x2 so the two x-slot register pairs are never dynamically
//  indexed. Dummy LDS pad forces 1 block/CU. Exchange protocol unchanged:
//  dual-plane tagged h words, bounded sc0 fast poll -> sc1 fallback.

#define T_STEPS 512
#define BATCH   256
#define DIN     128
#define HID     256
#define KDIM    384
#define LDK     392   // padded LDS row stride (shorts)
#define GRIDN   256
#define NPOLL   96    // bounded fast-poll tries before sc1 fallback

typedef __attribute__((ext_vector_type(8))) short short8;
typedef __attribute__((ext_vector_type(4))) short short4v;
typedef __attribute__((ext_vector_type(4))) float f32x4;

__device__ __forceinline__ unsigned short f2bf(float f) {
    unsigned u = __float_as_uint(f);
    unsigned r = (u + 0x7FFFu + ((u >> 16) & 1u)) >> 16;
    return (unsigned short)r;
}
__device__ __forceinline__ float bf2f(unsigned short s) {
    return __uint_as_float(((unsigned)s) << 16);
}
__device__ __forceinline__ float sigmoid_f(float x) {
    return 1.f / (1.f + __expf(-x));
}
__device__ __forceinline__ float tanh_f(float x) {
    float e = __expf(2.f * x);
    return 1.f - 2.f / (e + 1.f);
}
// execution barrier + LDS visibility, WITHOUT draining vmcnt (prefetch lives)
__device__ __forceinline__ void barrier_lds() {
    asm volatile("s_waitcnt lgkmcnt(0)" ::: "memory");
    __builtin_amdgcn_s_barrier();
}
// ---- fused poll loads: 4 x dwordx4 + waitcnt in ONE asm block (proven) ----
__device__ __forceinline__ void poll_load_sc0(const unsigned int* p, uint4& a,
                                              uint4& b, uint4& c, uint4& d) {
    asm volatile(
        "global_load_dwordx4 %0, %4, off sc0\n\t"
        "global_load_dwordx4 %1, %4, off offset:16 sc0\n\t"
        "global_load_dwordx4 %2, %4, off offset:32 sc0\n\t"
        "global_load_dwordx4 %3, %4, off offset:48 sc0\n\t"
        "s_waitcnt vmcnt(0)"
        : "=&v"(a), "=&v"(b), "=&v"(c), "=&v"(d) : "v"(p) : "memory");
}
__device__ __forceinline__ void poll_load_sc1(const unsigned int* p, uint4& a,
                                              uint4& b, uint4& c, uint4& d) {
    asm volatile(
        "global_load_dwordx4 %0, %4, off sc1\n\t"
        "global_load_dwordx4 %1, %4, off offset:16 sc1\n\t"
        "global_load_dwordx4 %2, %4, off offset:32 sc1\n\t"
        "global_load_dwordx4 %3, %4, off offset:48 sc1\n\t"
        "s_waitcnt vmcnt(0)"
        : "=&v"(a), "=&v"(b), "=&v"(c), "=&v"(d) : "v"(p) : "memory");
}
__device__ __forceinline__ void store_plain_u32(unsigned int* p, unsigned int v) {
    asm volatile("global_store_dword %0, %1, off" :: "v"(p), "v"(v) : "memory");
}
__device__ __forceinline__ void store_sc1_u32(unsigned int* p, unsigned int v) {
    asm volatile("global_store_dword %0, %1, off sc1" :: "v"(p), "v"(v) : "memory");
}
__device__ __forceinline__ unsigned pack2bf(unsigned lo, unsigned hi) {
    return (hi & 0xFFFF0000u) | (lo >> 16);
}
__device__ __forceinline__ bool tags_ok(const uint4& a, const uint4& b,
                                        const uint4& c, const uint4& d,
                                        unsigned tag) {
    return ((a.x ^ tag) & 0xFFFFu) == 0 && ((a.y ^ tag) & 0xFFFFu) == 0 &&
           ((a.z ^ tag) & 0xFFFFu) == 0 && ((a.w ^ tag) & 0xFFFFu) == 0 &&
           ((b.x ^ tag) & 0xFFFFu) == 0 && ((b.y ^ tag) & 0xFFFFu) == 0 &&
           ((b.z ^ tag) & 0xFFFFu) == 0 && ((b.w ^ tag) & 0xFFFFu) == 0 &&
           ((c.x ^ tag) & 0xFFFFu) == 0 && ((c.y ^ tag) & 0xFFFFu) == 0 &&
           ((c.z ^ tag) & 0xFFFFu) == 0 && ((c.w ^ tag) & 0xFFFFu) == 0 &&
           ((d.x ^ tag) & 0xFFFFu) == 0 && ((d.y ^ tag) & 0xFFFFu) == 0 &&
           ((d.z ^ tag) & 0xFFFFu) == 0 && ((d.w ^ tag) & 0xFFFFu) == 0;
}

// ---- pack weights: Wpack[n][k] bf16, n = g*256 + j, row-major [1024][384] ----
__global__ __launch_bounds__(256) void pack_w(
    const float* __restrict__ Wf, const float* __restrict__ Wi,
    const float* __restrict__ Wg, const float* __restrict__ Wo,
    unsigned short* __restrict__ Wp) {
    int idx = blockIdx.x * 256 + threadIdx.x;
    int n = idx / KDIM;
    int k = idx - n * KDIM;
    int g = n >> 8, j = n & 255;
    const float* s = (g == 0) ? Wf : (g == 1) ? Wi : (g == 2) ? Wg : Wo;
    Wp[idx] = f2bf(s[j * KDIM + k]);
}

__global__ __launch_bounds__(256) void pack_b(
    const float* __restrict__ bf, const float* __restrict__ bi,
    const float* __restrict__ bg, const float* __restrict__ bo,
    float* __restrict__ bp) {
    int n = blockIdx.x * 256 + threadIdx.x;
    int g = n >> 8, j = n & 255;
    const float* s = (g == 0) ? bf : (g == 1) ? bi : (g == 2) ? bg : bo;
    bp[n] = s[j];
}

// ---- zero all 4 exchange planes: fast[2] + slow[2] (h_0 = 0, tag 0) ----
__global__ __launch_bounds__(256) void init_k(unsigned int* __restrict__ hxp) {
    int tid = blockIdx.x * 256 + threadIdx.x;   // grid 256 -> 65536
    hxp[tid] = 0u;
    hxp[65536 + tid] = 0u;
    hxp[131072 + tid] = 0u;
    hxp[196608 + tid] = 0u;
}

// ================= one LSTM step (macro: xc0/xc1 are this parity's regs) ====
#define LSTM_STEP(kk, xc0, xc1)                                               \
    {                                                                         \
        const unsigned tag = (unsigned)(kk);                                  \
        /* stage x_k from 2-step-old prefetched regs */                       \
        {                                                                     \
            short4v r;                                                        \
            r.x = (short)f2bf(xc0.x); r.y = (short)f2bf(xc0.y);               \
            r.z = (short)f2bf(xc0.z); r.w = (short)f2bf(xc0.w);               \
            *(short4v*)(&comb_s[xr0 * LDK + xc4 * 4]) = r;                    \
            r.x = (short)f2bf(xc1.x); r.y = (short)f2bf(xc1.y);               \
            r.z = (short)f2bf(xc1.z); r.w = (short)f2bf(xc1.w);               \
            *(short4v*)(&comb_s[xr1 * LDK + xc4 * 4]) = r;                    \
        }                                                                     \
        const unsigned int* fb =                                              \
            hxp + ((kk) & 1) * 65536 + (b0 + hrow) * HID + hc * 16;           \
        const unsigned int* sb = fb + 131072;                                 \
        uint4 a, bq, cq, d;                                                   \
        const int usefast = fastok_s;                                         \
        if (usefast) {                                                        \
            int tries = NPOLL;                                                \
            bool ok = false;                                                  \
            for (;;) {                                                        \
                poll_load_sc0(fb, a, bq, cq, d);                              \
                if (tags_ok(a, bq, cq, d, tag)) { ok = true; break; }         \
                if (--tries == 0) break;                                      \
            }                                                                 \
            if (!ok) {                                                        \
                fastok_s = 0;                                                 \
                for (;;) {                                                    \
                    poll_load_sc1(sb, a, bq, cq, d);                          \
                    if (tags_ok(a, bq, cq, d, tag)) break;                    \
                    __builtin_amdgcn_s_sleep(1);                              \
                }                                                             \
            }                                                                 \
        } else {                                                              \
            for (;;) {                                                        \
                poll_load_sc1(sb, a, bq, cq, d);                              \
                if (tags_ok(a, bq, cq, d, tag)) break;                        \
                __builtin_amdgcn_s_sleep(1);                                  \
            }                                                                 \
        }                                                                     \
        /* extract 16 bf16 -> comb_s[hrow][DIN + hc*16 ..] */                 \
        {                                                                     \
            uint4 p0, p1;                                                     \
            p0.x = pack2bf(a.x, a.y);   p0.y = pack2bf(a.z, a.w);             \
            p0.z = pack2bf(bq.x, bq.y); p0.w = pack2bf(bq.z, bq.w);           \
            p1.x = pack2bf(cq.x, cq.y); p1.y = pack2bf(cq.z, cq.w);           \
            p1.z = pack2bf(d.x, d.y);   p1.w = pack2bf(d.z, d.w);             \
            *(uint4*)(&comb_s[hrow * LDK + DIN + hc * 16]) = p0;              \
            *(uint4*)(&comb_s[hrow * LDK + DIN + hc * 16 + 8]) = p1;          \
        }                                                                     \
        /* prefetch x_{k+2} into the SAME slot regs (post-poll: vmcnt clean) */\
        if ((kk) + 2 < T_STEPS) {                                             \
            const float* xn = X + (size_t)((kk) + 2) * BATCH * DIN + b0 * DIN;\
            xc0 = *(const float4*)(xn + xr0 * DIN + xc4 * 4);                 \
            xc1 = *(const float4*)(xn + xr1 * DIN + xc4 * 4);                 \
        }                                                                     \
        barrier_lds();                                                        \
        /* MFMA: A from comb_s, B from registers (wf) */                      \
        f32x4 acc0 = {0.f, 0.f, 0.f, 0.f}, acc1 = {0.f, 0.f, 0.f, 0.f};       \
        _Pragma("unroll")                                                     \
        for (int kt = 0; kt < 6; ++kt) {                                      \
            short8 a0 = *(const short8*)(arow + (2 * kt) * 32);               \
            short8 a1 = *(const short8*)(arow + (2 * kt + 1) * 32);           \
            acc0 = __builtin_amdgcn_mfma_f32_16x16x32_bf16(a0, wf[2 * kt],    \
                                                           acc0, 0, 0, 0);    \
            acc1 = __builtin_amdgcn_mfma_f32_16x16x32_bf16(a1, wf[2 * kt + 1],\
                                                           acc1, 0, 0, 0);    \
        }                                                                     \
        _Pragma("unroll")                                                     \
        for (int r = 0; r < 4; ++r)                                           \
            z_s[wave * 272 + (quad * 4 + r) * 17 + l16] = acc0[r] + acc1[r];  \
        barrier_lds();                                                        \
        /* gates; c in register; dual-plane h store + history */              \
        float zf = z_s[0 * 272 + bi * 17 + jj] + bs0;                         \
        float zi = z_s[1 * 272 + bi * 17 + jj] + bs1;                         \
        float zg = z_s[2 * 272 + bi * 17 + jj] + bs2;                         \
        float zo = z_s[3 * 272 + bi * 17 + jj] + bs3;                         \
        float fg = sigmoid_f(zf);                                             \
        float ig = sigmoid_f(zi);                                             \
        float gg = tanh_f(zg);                                                \
        float og = sigmoid_f(zo);                                             \
        c_reg = fg * c_reg + ig * gg;                                         \
        float hval = og * tanh_f(c_reg);                                      \
        unsigned short hb = f2bf(hval);                                       \
        unsigned int hword = ((unsigned)hb << 16) | (unsigned)((kk) + 1);     \
        unsigned int* fdst = hxp + (((kk) + 1) & 1) * 65536 + b * HID + j;    \
        store_plain_u32(fdst, hword);                                         \
        store_sc1_u32(fdst + 131072, hword);                                  \
        hist[(size_t)(kk) * BATCH * HID + b * HID + j] = hb;                  \
        if ((kk) == T_STEPS - 1) { h_final = hval; }                          \
    }

// ---- persistent LSTM: all 512 steps in one launch ----
__global__ __launch_bounds__(256, 1) void lstm_persist(
    const float* __restrict__ X,            // [T,B,D] fp32
    const unsigned short* __restrict__ W,   // [1024][384] bf16
    const float* __restrict__ bias,         // [1024]
    unsigned int* __restrict__ hxp,         // fast[2][B][H] + slow[2][B][H]
    unsigned short* __restrict__ hist,      // [T][B][H] bf16
    float* __restrict__ out) {
    __shared__ __align__(16) unsigned short comb_s[16 * LDK]; // 12544 B
    __shared__ __align__(16) float z_s[4 * 272];              // 4352 B
    __shared__ char lds_pad[68000];                           // force 1 block/CU
    __shared__ int fastok_s;

    const int tid = threadIdx.x;
    // chain = same (blockIdx % 16): XCD-local under round-robin dispatch
    const int bg = blockIdx.x & 15, jg = blockIdx.x >> 4;
    const int b0 = bg * 16, j0 = jg * 16;
    const int wave = tid >> 6, lane = tid & 63;
    const int l16 = lane & 15, quad = lane >> 4;
    const int bi = tid >> 4, jj = tid & 15;
    const int b = b0 + bi, j = j0 + jj;

    if (tid == 0) { fastok_s = 1; lds_pad[0] = (char)blockIdx.x; }
    (void)lds_pad;

    // ---- W B-fragments into registers, ONCE (wave g = gate g) ----
    short8 wf[12];
    {
        const unsigned short* wbase =
            W + (wave * 256 + j0 + l16) * KDIM + quad * 8;
#pragma unroll
        for (int kt = 0; kt < 12; ++kt)
            wf[kt] = *(const short8*)(wbase + kt * 32);
    }
    const float bs0 = bias[0 * HID + j];
    const float bs1 = bias[1 * HID + j];
    const float bs2 = bias[2 * HID + j];
    const float bs3 = bias[3 * HID + j];

    float c_reg = 0.f;
    float h_final = 0.f;

    const unsigned short* arow = &comb_s[l16 * LDK + quad * 8];
    const int hrow = tid >> 4, hc = tid & 15;
    const int xr0 = tid >> 5, xc4 = tid & 31, xr1 = (tid + 256) >> 5;

    // preload x_0 (even slot) and x_1 (odd slot)
    const float* xb0p = X + b0 * DIN;
    const float* xb1p = X + (size_t)BATCH * DIN + b0 * DIN;
    float4 xa0 = *(const float4*)(xb0p + xr0 * DIN + xc4 * 4);
    float4 xa1 = *(const float4*)(xb0p + xr1 * DIN + xc4 * 4);
    float4 xb0 = *(const float4*)(xb1p + xr0 * DIN + xc4 * 4);
    float4 xb1 = *(const float4*)(xb1p + xr1 * DIN + xc4 * 4);

    __syncthreads();

    for (int k = 0; k < T_STEPS; k += 2) {
        LSTM_STEP(k, xa0, xa1);
        LSTM_STEP(k + 1, xb0, xb1);
    }

    // epilogue: hx (fp32) and cx outputs
    out[T_STEPS * BATCH * 2 + b * HID + j] = h_final;
    out[T_STEPS * BATCH * 2 + BATCH * HID + b * HID + j] = c_reg;
}

// ---- classifier head: one wave per (t,b) row ----
__global__ __launch_bounds__(256) void probs_k(
    const unsigned short* __restrict__ hist, const float* __restrict__ Wc,
    const float* __restrict__ bc, float* __restrict__ out) {
    const int wave = threadIdx.x >> 6, lane = threadIdx.x & 63;
    const size_t row = (size_t)blockIdx.x * 4 + wave;   // row = t*256+b < 131072
    const unsigned short* h = hist + row * HID;
    short4v hv = *(const short4v*)(h + lane * 4);
    const float4 wv = *(const float4*)(Wc + lane * 4);
    float p = bf2f((unsigned short)hv.x) * wv.x + bf2f((unsigned short)hv.y) * wv.y +
              bf2f((unsigned short)hv.z) * wv.z + bf2f((unsigned short)hv.w) * wv.w;
#pragma unroll
    for (int off = 32; off >= 1; off >>= 1) p += __shfl_down(p, off);
    if (lane == 0) {
        float prob = 1.f / (1.f + __expf(-(p + bc[0])));
        out[row * 2]     = prob;
        out[row * 2 + 1] = 1.f - prob;
    }
}

extern "C" void kernel_launch(void* const* d_in, const int* in_sizes, int n_in,
                              void* d_out, int out_size, void* d_ws, size_t ws_size,
                              hipStream_t stream) {
    const float* X  = (const float*)d_in[0];
    const float* Wf = (const float*)d_in[1];
    const float* bfp= (const float*)d_in[2];
    const float* Wi = (const float*)d_in[3];
    const float* bip= (const float*)d_in[4];
    const float* Wg = (const float*)d_in[5];
    const float* bgp= (const float*)d_in[6];
    const float* Wo = (const float*)d_in[7];
    const float* bop= (const float*)d_in[8];
    const float* Wc = (const float*)d_in[9];
    const float* bc = (const float*)d_in[10];
    float* out = (float*)d_out;

    char* ws = (char*)d_ws;
    unsigned short* Wpack = (unsigned short*)(ws);               // 786432 B
    float* bias = (float*)(ws + 786432);                         // 4096 B
    unsigned int* hxp = (unsigned int*)(ws + 790528);            // 1048576 B
    unsigned short* hist = (unsigned short*)(ws + 1839104);      // 67108864 B

    pack_w<<<1536, 256, 0, stream>>>(Wf, Wi, Wg, Wo, Wpack);
    pack_b<<<4, 256, 0, stream>>>(bfp, bip, bgp, bop, bias);
    init_k<<<256, 256, 0, stream>>>(hxp);

    void* kargs[6] = {(void*)&X, (void*)&Wpack, (void*)&bias,
                      (void*)&hxp, (void*)&hist, (void*)&out};
    (void)hipLaunchCooperativeKernel((const void*)lstm_persist, dim3(GRIDN),
                                     dim3(256), kargs, 0, stream);

    probs_k<<<32768, 256, 0, stream>>>(hist, Wc, bc, out);
}